// Round 1
// baseline (537.731 us; speedup 1.0000x reference)
//
#include <hip/hip_runtime.h>
#include <stdint.h>

#define Bb 2
#define Ss 2048
#define Dd 2048
#define NHh 16
#define NKVv 4
#define DHh 128
#define Mm_ (Bb*Ss)        // 4096
#define NQq (NHh*DHh)      // 2048

using bf16x8 = __attribute__((ext_vector_type(8))) __bf16;
using f32x4  = __attribute__((ext_vector_type(4))) float;

__device__ __forceinline__ unsigned short f2bf(float f) {
  unsigned u = __float_as_uint(f);
  u += 0x7fffu + ((u >> 16) & 1u);
  return (unsigned short)(u >> 16);
}
__device__ __forceinline__ float bf2f(unsigned short s) {
  return __uint_as_float(((unsigned)s) << 16);
}

// ---------------- elementwise f32 -> bf16 convert ----------------
__global__ void k_convert(const float* __restrict__ in, unsigned short* __restrict__ out, int n4) {
  const int i = blockIdx.x * blockDim.x + threadIdx.x;
  if (i >= n4) return;
  const float4 v = ((const float4*)in)[i];
  ushort4 o;
  o.x = f2bf(v.x); o.y = f2bf(v.y); o.z = f2bf(v.z); o.w = f2bf(v.w);
  ((ushort4*)out)[i] = o;
}

// ---------------- W (K x N, f32) -> W^T (N x K, bf16) ----------------
__global__ __launch_bounds__(256) void k_transpose(const float* __restrict__ in,
                                                   unsigned short* __restrict__ out,
                                                   int Kk, int Nn) {
  __shared__ float tile[32][33];
  const int n0 = blockIdx.x * 32, k0 = blockIdx.y * 32;
  const int tx = threadIdx.x & 31, ty = threadIdx.x >> 5;  // 256 = 32x8
  #pragma unroll
  for (int i = 0; i < 4; ++i)
    tile[ty + i * 8][tx] = in[(size_t)(k0 + ty + i * 8) * Nn + n0 + tx];
  __syncthreads();
  #pragma unroll
  for (int i = 0; i < 4; ++i)
    out[(size_t)(n0 + ty + i * 8) * Kk + k0 + tx] = f2bf(tile[tx][ty + i * 8]);
}

// ---------------- bf16 GEMM: C[M,N] = A[M,K] @ BT[N,K]^T ----------------
// 128x128 tile, 4 waves (2x2), 16x16x32 MFMA, global_load_lds staging.
__global__ __launch_bounds__(256) void k_gemm_bt(const unsigned short* __restrict__ A,
                                                 const unsigned short* __restrict__ BT,
                                                 float* __restrict__ Cf,
                                                 unsigned short* __restrict__ Cb,
                                                 int Nn, int Kk) {
  __shared__ unsigned short As[4096];  // [128][32]
  __shared__ unsigned short Bs[4096];  // [128][32]
  const int tid = threadIdx.x, wid = tid >> 6, lane = tid & 63;
  const int lg = lane >> 4, ll = lane & 15;
  const int wm = wid >> 1, wn = wid & 1;
  const int m0 = blockIdx.y << 7, n0 = blockIdx.x << 7;
  f32x4 acc[4][4] = {};
  const int nk = Kk >> 5;
  for (int kk = 0; kk < nk; ++kk) {
    const int k0 = kk << 5;
    __syncthreads();
    #pragma unroll
    for (int i = 0; i < 2; ++i) {
      const int call = wid * 2 + i;
      const int c = call * 64 + lane;
      const int row = c >> 2, ce = (c & 3) * 8;
      const unsigned short* ga = A  + (size_t)(m0 + row) * Kk + k0 + ce;
      const unsigned short* gb = BT + (size_t)(n0 + row) * Kk + k0 + ce;
      __builtin_amdgcn_global_load_lds(
          (const __attribute__((address_space(1))) void*)ga,
          (__attribute__((address_space(3))) void*)(As + call * 512), 16, 0, 0);
      __builtin_amdgcn_global_load_lds(
          (const __attribute__((address_space(1))) void*)gb,
          (__attribute__((address_space(3))) void*)(Bs + call * 512), 16, 0, 0);
    }
    __syncthreads();
    bf16x8 af[4], bfr[4];
    #pragma unroll
    for (int rb = 0; rb < 4; ++rb)
      af[rb] = *(const bf16x8*)(const void*)(As + (wm * 64 + rb * 16 + ll) * 32 + lg * 8);
    #pragma unroll
    for (int cb = 0; cb < 4; ++cb)
      bfr[cb] = *(const bf16x8*)(const void*)(Bs + (wn * 64 + cb * 16 + ll) * 32 + lg * 8);
    #pragma unroll
    for (int rb = 0; rb < 4; ++rb)
      #pragma unroll
      for (int cb = 0; cb < 4; ++cb)
        acc[rb][cb] = __builtin_amdgcn_mfma_f32_16x16x32_bf16(af[rb], bfr[cb], acc[rb][cb], 0, 0, 0);
  }
  #pragma unroll
  for (int rb = 0; rb < 4; ++rb)
    #pragma unroll
    for (int cb = 0; cb < 4; ++cb) {
      const int row = m0 + wm * 64 + rb * 16 + lg * 4;
      const int col = n0 + wn * 64 + cb * 16 + ll;
      #pragma unroll
      for (int jj = 0; jj < 4; ++jj) {
        if (Cf) Cf[(size_t)(row + jj) * Nn + col] = acc[rb][cb][jj];
        else    Cb[(size_t)(row + jj) * Nn + col] = f2bf(acc[rb][cb][jj]);
      }
    }
}

// ---------------- RoPE on q (in-place bf16), folds 1/sqrt(DH) ----------------
__global__ void k_rope_q(unsigned short* __restrict__ q, const float* __restrict__ cosT,
                         const float* __restrict__ sinT) {
  const int idx = blockIdx.x * blockDim.x + threadIdx.x;
  if (idx >= Mm_ * NHh * 64) return;
  const int dh2 = idx & 63;
  const int h = (idx >> 6) & 15;
  const int m = idx >> 10;
  const int s = m & (Ss - 1);
  const size_t base = (size_t)m * NQq + h * DHh + dh2;
  const float x1 = bf2f(q[base]), x2 = bf2f(q[base + 64]);
  const float c = cosT[s * 64 + dh2], sn = sinT[s * 64 + dh2];
  const float sc = 0.08838834764831845f;  // 1/sqrt(128)
  q[base]      = f2bf((x1 * c - x2 * sn) * sc);
  q[base + 64] = f2bf((x1 * sn + x2 * c) * sc);
}

// ---------------- RoPE on k: f32 cache out + bf16 copy ----------------
__global__ void k_rope_k(const float* __restrict__ kf, const float* __restrict__ cosT,
                         const float* __restrict__ sinT, float* __restrict__ outK,
                         unsigned short* __restrict__ kbb) {
  const int idx = blockIdx.x * blockDim.x + threadIdx.x;
  if (idx >= Mm_ * NKVv * 64) return;
  const int dh2 = idx & 63;
  const int kv = (idx >> 6) & 3;
  const int m = idx >> 8;
  const int s = m & (Ss - 1);
  const int b = m >> 11;
  const size_t src = (size_t)m * 512 + kv * DHh + dh2;
  const float x1 = kf[src], x2 = kf[src + 64];
  const float c = cosT[s * 64 + dh2], sn = sinT[s * 64 + dh2];
  const float o1 = x1 * c - x2 * sn, o2 = x1 * sn + x2 * c;
  const size_t dst = ((size_t)(b * NKVv + kv) * Ss + s) * DHh + dh2;
  outK[dst] = o1; outK[dst + 64] = o2;
  kbb[dst] = f2bf(o1); kbb[dst + 64] = f2bf(o2);
}

// ---------------- v: f32 cache out + bf16 transposed copy ----------------
__global__ void k_v_post(const float* __restrict__ vf, float* __restrict__ outV,
                         unsigned short* __restrict__ vTb) {
  const int idx = blockIdx.x * blockDim.x + threadIdx.x;
  if (idx >= Mm_ * NKVv * DHh) return;
  const int dh = idx & 127;
  const int kv = (idx >> 7) & 3;
  const int m = idx >> 9;
  const int s = m & (Ss - 1);
  const int b = m >> 11;
  const float v = vf[(size_t)m * 512 + kv * DHh + dh];
  outV[((size_t)(b * NKVv + kv) * Ss + s) * DHh + dh] = v;
  vTb[((size_t)(b * NKVv + kv) * DHh + dh) * Ss + s] = f2bf(v);
}

// ---------------- causal flash attention ----------------
// grid (S/64, B*NH); 4 waves, each owns 16 q-rows. KBLK=64.
__global__ __launch_bounds__(256) void k_attn(const unsigned short* __restrict__ qb,
                                              const unsigned short* __restrict__ kb,
                                              const unsigned short* __restrict__ vT,
                                              unsigned short* __restrict__ ctxb) {
  const int qtile = blockIdx.x;
  const int bh = blockIdx.y;
  const int b = bh >> 4, h = bh & 15;
  const int kvh = h >> 2;
  const int tid = threadIdx.x, wid = tid >> 6, lane = tid & 63;
  const int lg = lane >> 4, ll = lane & 15;
  __shared__ unsigned short kt_s[64 * 128];   // [key][dh]
  __shared__ unsigned short vt_s[128 * 64];   // [dh][key]
  __shared__ unsigned short p_s[4][16][64];   // per-wave P
  const unsigned short* kbase = kb + (size_t)(b * NKVv + kvh) * Ss * DHh;
  const unsigned short* vbase = vT + (size_t)(b * NKVv + kvh) * DHh * Ss;
  const int qrow_f = qtile * 64 + wid * 16 + ll;
  const unsigned short* qrow = qb + (size_t)(b * Ss + qrow_f) * NQq + h * DHh;
  bf16x8 qfr[4];
  #pragma unroll
  for (int ks = 0; ks < 4; ++ks)
    qfr[ks] = *(const bf16x8*)(const void*)(qrow + ks * 32 + lg * 8);
  f32x4 ctx[8] = {};
  float m_i[4], l_i[4];
  #pragma unroll
  for (int j = 0; j < 4; ++j) { m_i[j] = -1e30f; l_i[j] = 0.f; }
  const int qr0 = qtile * 64 + wid * 16 + lg * 4;
  const int nkt = qtile + 1;
  for (int kt = 0; kt < nkt; ++kt) {
    __syncthreads();
    {
      const uint4* srck = (const uint4*)(const void*)(kbase + (size_t)kt * 64 * DHh);
      uint4* dk = (uint4*)(void*)kt_s;
      #pragma unroll
      for (int i = 0; i < 4; ++i) dk[tid + i * 256] = srck[tid + i * 256];
      uint4* dv = (uint4*)(void*)vt_s;
      #pragma unroll
      for (int i = 0; i < 4; ++i) {
        const int c = tid + i * 256;
        dv[c] = *(const uint4*)(const void*)(vbase + (size_t)(c >> 3) * Ss + kt * 64 + (c & 7) * 8);
      }
    }
    __syncthreads();
    f32x4 sc[4] = {};
    #pragma unroll
    for (int ks = 0; ks < 4; ++ks) {
      #pragma unroll
      for (int cb = 0; cb < 4; ++cb) {
        const bf16x8 kfr = *(const bf16x8*)(const void*)(kt_s + (cb * 16 + ll) * DHh + ks * 32 + lg * 8);
        sc[cb] = __builtin_amdgcn_mfma_f32_16x16x32_bf16(qfr[ks], kfr, sc[cb], 0, 0, 0);
      }
    }
    float pv[4][4], pmax[4];
    #pragma unroll
    for (int j = 0; j < 4; ++j) pmax[j] = -1e30f;
    const int keyb = kt * 64 + ll;
    #pragma unroll
    for (int cb = 0; cb < 4; ++cb)
      #pragma unroll
      for (int j = 0; j < 4; ++j) {
        float s = sc[cb][j];
        if (keyb + cb * 16 > qr0 + j) s = -1e30f;  // causal
        pv[cb][j] = s;
        pmax[j] = fmaxf(pmax[j], s);
      }
    #pragma unroll
    for (int j = 0; j < 4; ++j) {
      #pragma unroll
      for (int msk = 1; msk < 16; msk <<= 1)
        pmax[j] = fmaxf(pmax[j], __shfl_xor(pmax[j], msk));
    }
    float corr[4], psum[4];
    #pragma unroll
    for (int j = 0; j < 4; ++j) {
      const float mn = fmaxf(m_i[j], pmax[j]);
      corr[j] = __expf(m_i[j] - mn);
      m_i[j] = mn;
      psum[j] = 0.f;
    }
    #pragma unroll
    for (int cb = 0; cb < 4; ++cb)
      #pragma unroll
      for (int j = 0; j < 4; ++j) {
        const float p = __expf(pv[cb][j] - m_i[j]);
        pv[cb][j] = p;
        psum[j] += p;
      }
    #pragma unroll
    for (int j = 0; j < 4; ++j) {
      #pragma unroll
      for (int msk = 1; msk < 16; msk <<= 1)
        psum[j] += __shfl_xor(psum[j], msk);
      l_i[j] = l_i[j] * corr[j] + psum[j];
    }
    #pragma unroll
    for (int ob = 0; ob < 8; ++ob)
      #pragma unroll
      for (int j = 0; j < 4; ++j) ctx[ob][j] *= corr[j];
    #pragma unroll
    for (int cb = 0; cb < 4; ++cb)
      #pragma unroll
      for (int j = 0; j < 4; ++j)
        p_s[wid][lg * 4 + j][cb * 16 + ll] = f2bf(pv[cb][j]);
    __syncthreads();
    #pragma unroll
    for (int k2 = 0; k2 < 2; ++k2) {
      const bf16x8 pa = *(const bf16x8*)(const void*)(&p_s[wid][ll][k2 * 32 + lg * 8]);
      #pragma unroll
      for (int ob = 0; ob < 8; ++ob) {
        const bf16x8 vfr = *(const bf16x8*)(const void*)(vt_s + (ob * 16 + ll) * 64 + k2 * 32 + lg * 8);
        ctx[ob] = __builtin_amdgcn_mfma_f32_16x16x32_bf16(pa, vfr, ctx[ob], 0, 0, 0);
      }
    }
  }
  #pragma unroll
  for (int j = 0; j < 4; ++j) {
    const float inv = 1.f / l_i[j];
    unsigned short* crow = ctxb + (size_t)(b * Ss + qr0 + j) * NQq + h * DHh;
    #pragma unroll
    for (int ob = 0; ob < 8; ++ob)
      crow[ob * 16 + ll] = f2bf(ctx[ob][j] * inv);
  }
}

extern "C" void kernel_launch(void* const* d_in, const int* in_sizes, int n_in,
                              void* d_out, int out_size, void* d_ws, size_t ws_size,
                              hipStream_t stream) {
  const float* x    = (const float*)d_in[0];
  const float* cosT = (const float*)d_in[1];
  const float* sinT = (const float*)d_in[2];
  // d_in[3] = mask (causal tril) -- implemented structurally
  const float* Wq   = (const float*)d_in[4];
  const float* Wk   = (const float*)d_in[5];
  const float* Wv   = (const float*)d_in[6];
  const float* Wo   = (const float*)d_in[7];
  float* out  = (float*)d_out;
  float* outK = out + (size_t)Mm_ * Dd;
  float* outV = outK + (size_t)Bb * NKVv * Ss * DHh;

  char* ws = (char*)d_ws;
  size_t off = 0;
  auto alloc = [&](size_t bytes) -> void* {
    void* p = ws + off;
    off += (bytes + 255) & ~(size_t)255;
    return p;
  };
  unsigned short* xb  = (unsigned short*)alloc((size_t)Mm_ * Dd * 2);
  unsigned short* wqT = (unsigned short*)alloc((size_t)NQq * Dd * 2);
  unsigned short* wkT = (unsigned short*)alloc((size_t)512 * Dd * 2);
  unsigned short* wvT = (unsigned short*)alloc((size_t)512 * Dd * 2);
  unsigned short* woT = (unsigned short*)alloc((size_t)Dd * NQq * 2);
  unsigned short* qfb = (unsigned short*)alloc((size_t)Mm_ * NQq * 2);
  float*          kf  = (float*)alloc((size_t)Mm_ * 512 * 4);
  float*          vf  = (float*)alloc((size_t)Mm_ * 512 * 4);
  unsigned short* kbb = (unsigned short*)alloc((size_t)Bb * NKVv * Ss * DHh * 2);
  unsigned short* vTb = (unsigned short*)alloc((size_t)Bb * NKVv * Ss * DHh * 2);
  unsigned short* ctxb= (unsigned short*)alloc((size_t)Mm_ * NQq * 2);
  if (off > ws_size) return;  // workspace too small: fail cleanly

  // 1. x -> bf16
  k_convert<<<(Mm_ * Dd / 4 + 255) / 256, 256, 0, stream>>>(x, xb, Mm_ * Dd / 4);
  // 2. weights -> bf16 transposed
  k_transpose<<<dim3(Dd / 32, Dd / 32), 256, 0, stream>>>(Wq, wqT, Dd, Dd);
  k_transpose<<<dim3(512 / 32, Dd / 32), 256, 0, stream>>>(Wk, wkT, Dd, 512);
  k_transpose<<<dim3(512 / 32, Dd / 32), 256, 0, stream>>>(Wv, wvT, Dd, 512);
  k_transpose<<<dim3(Dd / 32, Dd / 32), 256, 0, stream>>>(Wo, woT, Dd, Dd);
  // 3. projections
  k_gemm_bt<<<dim3(NQq / 128, Mm_ / 128), 256, 0, stream>>>(xb, wqT, (float*)nullptr, qfb, NQq, Dd);
  k_gemm_bt<<<dim3(512 / 128, Mm_ / 128), 256, 0, stream>>>(xb, wkT, kf, (unsigned short*)nullptr, 512, Dd);
  k_gemm_bt<<<dim3(512 / 128, Mm_ / 128), 256, 0, stream>>>(xb, wvT, vf, (unsigned short*)nullptr, 512, Dd);
  // 4. RoPE + cache outputs
  k_rope_k<<<(Mm_ * NKVv * 64 + 255) / 256, 256, 0, stream>>>(kf, cosT, sinT, outK, kbb);
  k_v_post<<<(Mm_ * NKVv * DHh + 255) / 256, 256, 0, stream>>>(vf, outV, vTb);
  k_rope_q<<<(Mm_ * NHh * 64 + 255) / 256, 256, 0, stream>>>(qfb, cosT, sinT);
  // 5. attention
  k_attn<<<dim3(Ss / 64, Bb * NHh), 256, 0, stream>>>(qfb, kbb, vTb, ctxb);
  // 6. output projection
  k_gemm_bt<<<dim3(Dd / 128, Mm_ / 128), 256, 0, stream>>>(ctxb, woT, out, (unsigned short*)nullptr, Dd, NQq);
}

// Round 2
// 400.391 us; speedup vs baseline: 1.3430x; 1.3430x over previous
//
#include <hip/hip_runtime.h>
#include <stdint.h>

#define Bb 2
#define Ss 2048
#define Dd 2048
#define NHh 16
#define NKVv 4
#define DHh 128
#define Mm_ (Bb*Ss)        // 4096
#define NQq (NHh*DHh)      // 2048

using bf16x8 = __attribute__((ext_vector_type(8))) __bf16;
using f32x4  = __attribute__((ext_vector_type(4))) float;

__device__ __forceinline__ unsigned short f2bf(float f) {
  unsigned u = __float_as_uint(f);
  u += 0x7fffu + ((u >> 16) & 1u);
  return (unsigned short)(u >> 16);
}
__device__ __forceinline__ float bf2f(unsigned short s) {
  return __uint_as_float(((unsigned)s) << 16);
}

// ---------------- elementwise f32 -> bf16 convert ----------------
__global__ void k_convert(const float* __restrict__ in, unsigned short* __restrict__ out, int n4) {
  const int i = blockIdx.x * blockDim.x + threadIdx.x;
  if (i >= n4) return;
  const float4 v = ((const float4*)in)[i];
  ushort4 o;
  o.x = f2bf(v.x); o.y = f2bf(v.y); o.z = f2bf(v.z); o.w = f2bf(v.w);
  ((ushort4*)out)[i] = o;
}

// ---------------- W (K x N, f32) -> W^T (N x K, bf16) ----------------
__global__ __launch_bounds__(256) void k_transpose(const float* __restrict__ in,
                                                   unsigned short* __restrict__ out,
                                                   int Kk, int Nn) {
  __shared__ float tile[32][33];
  const int n0 = blockIdx.x * 32, k0 = blockIdx.y * 32;
  const int tx = threadIdx.x & 31, ty = threadIdx.x >> 5;  // 256 = 32x8
  #pragma unroll
  for (int i = 0; i < 4; ++i)
    tile[ty + i * 8][tx] = in[(size_t)(k0 + ty + i * 8) * Nn + n0 + tx];
  __syncthreads();
  #pragma unroll
  for (int i = 0; i < 4; ++i)
    out[(size_t)(n0 + ty + i * 8) * Kk + k0 + tx] = f2bf(tile[tx][ty + i * 8]);
}

// ---------------- bf16 GEMM: C[M,N] = A[M,K] @ BT[N,K]^T ----------------
// 128x128 tile, 4 waves (2x2), 16x16x32 MFMA, global_load_lds staging.
__global__ __launch_bounds__(256) void k_gemm_bt(const unsigned short* __restrict__ A,
                                                 const unsigned short* __restrict__ BT,
                                                 float* __restrict__ Cf,
                                                 unsigned short* __restrict__ Cb,
                                                 int Nn, int Kk) {
  __shared__ unsigned short As[4096];  // [128][32]
  __shared__ unsigned short Bs[4096];  // [128][32]
  const int tid = threadIdx.x, wid = tid >> 6, lane = tid & 63;
  const int lg = lane >> 4, ll = lane & 15;
  const int wm = wid >> 1, wn = wid & 1;
  const int m0 = blockIdx.y << 7, n0 = blockIdx.x << 7;
  f32x4 acc[4][4] = {};
  const int nk = Kk >> 5;
  for (int kk = 0; kk < nk; ++kk) {
    const int k0 = kk << 5;
    __syncthreads();
    #pragma unroll
    for (int i = 0; i < 2; ++i) {
      const int call = wid * 2 + i;
      const int c = call * 64 + lane;
      const int row = c >> 2, ce = (c & 3) * 8;
      const unsigned short* ga = A  + (size_t)(m0 + row) * Kk + k0 + ce;
      const unsigned short* gb = BT + (size_t)(n0 + row) * Kk + k0 + ce;
      __builtin_amdgcn_global_load_lds(
          (const __attribute__((address_space(1))) void*)ga,
          (__attribute__((address_space(3))) void*)(As + call * 512), 16, 0, 0);
      __builtin_amdgcn_global_load_lds(
          (const __attribute__((address_space(1))) void*)gb,
          (__attribute__((address_space(3))) void*)(Bs + call * 512), 16, 0, 0);
    }
    __syncthreads();
    bf16x8 af[4], bfr[4];
    #pragma unroll
    for (int rb = 0; rb < 4; ++rb)
      af[rb] = *(const bf16x8*)(const void*)(As + (wm * 64 + rb * 16 + ll) * 32 + lg * 8);
    #pragma unroll
    for (int cb = 0; cb < 4; ++cb)
      bfr[cb] = *(const bf16x8*)(const void*)(Bs + (wn * 64 + cb * 16 + ll) * 32 + lg * 8);
    #pragma unroll
    for (int rb = 0; rb < 4; ++rb)
      #pragma unroll
      for (int cb = 0; cb < 4; ++cb)
        acc[rb][cb] = __builtin_amdgcn_mfma_f32_16x16x32_bf16(af[rb], bfr[cb], acc[rb][cb], 0, 0, 0);
  }
  #pragma unroll
  for (int rb = 0; rb < 4; ++rb)
    #pragma unroll
    for (int cb = 0; cb < 4; ++cb) {
      const int row = m0 + wm * 64 + rb * 16 + lg * 4;
      const int col = n0 + wn * 64 + cb * 16 + ll;
      #pragma unroll
      for (int jj = 0; jj < 4; ++jj) {
        if (Cf) Cf[(size_t)(row + jj) * Nn + col] = acc[rb][cb][jj];
        else    Cb[(size_t)(row + jj) * Nn + col] = f2bf(acc[rb][cb][jj]);
      }
    }
}

// ---------------- RoPE on q (in-place bf16), folds 1/sqrt(DH) ----------------
__global__ void k_rope_q(unsigned short* __restrict__ q, const float* __restrict__ cosT,
                         const float* __restrict__ sinT) {
  const int idx = blockIdx.x * blockDim.x + threadIdx.x;
  if (idx >= Mm_ * NHh * 64) return;
  const int dh2 = idx & 63;
  const int h = (idx >> 6) & 15;
  const int m = idx >> 10;
  const int s = m & (Ss - 1);
  const size_t base = (size_t)m * NQq + h * DHh + dh2;
  const float x1 = bf2f(q[base]), x2 = bf2f(q[base + 64]);
  const float c = cosT[s * 64 + dh2], sn = sinT[s * 64 + dh2];
  const float sc = 0.08838834764831845f;  // 1/sqrt(128)
  q[base]      = f2bf((x1 * c - x2 * sn) * sc);
  q[base + 64] = f2bf((x1 * sn + x2 * c) * sc);
}

// ---------------- RoPE on k: f32 cache out + bf16 copy ----------------
__global__ void k_rope_k(const float* __restrict__ kf, const float* __restrict__ cosT,
                         const float* __restrict__ sinT, float* __restrict__ outK,
                         unsigned short* __restrict__ kbb) {
  const int idx = blockIdx.x * blockDim.x + threadIdx.x;
  if (idx >= Mm_ * NKVv * 64) return;
  const int dh2 = idx & 63;
  const int kv = (idx >> 6) & 3;
  const int m = idx >> 8;
  const int s = m & (Ss - 1);
  const int b = m >> 11;
  const size_t src = (size_t)m * 512 + kv * DHh + dh2;
  const float x1 = kf[src], x2 = kf[src + 64];
  const float c = cosT[s * 64 + dh2], sn = sinT[s * 64 + dh2];
  const float o1 = x1 * c - x2 * sn, o2 = x1 * sn + x2 * c;
  const size_t dst = ((size_t)(b * NKVv + kv) * Ss + s) * DHh + dh2;
  outK[dst] = o1; outK[dst + 64] = o2;
  kbb[dst] = f2bf(o1); kbb[dst + 64] = f2bf(o2);
}

// ---------------- v: f32 cache out + bf16 transposed copy ----------------
__global__ void k_v_post(const float* __restrict__ vf, float* __restrict__ outV,
                         unsigned short* __restrict__ vTb) {
  const int idx = blockIdx.x * blockDim.x + threadIdx.x;
  if (idx >= Mm_ * NKVv * DHh) return;
  const int dh = idx & 127;
  const int kv = (idx >> 7) & 3;
  const int m = idx >> 9;
  const int s = m & (Ss - 1);
  const int b = m >> 11;
  const float v = vf[(size_t)m * 512 + kv * DHh + dh];
  outV[((size_t)(b * NKVv + kv) * Ss + s) * DHh + dh] = v;
  vTb[((size_t)(b * NKVv + kv) * DHh + dh) * Ss + s] = f2bf(v);
}

// ---------------- causal flash attention ----------------
// grid (32, 32) remapped so each CU's 4 co-resident blocks have balanced
// causal workloads. 4 waves, each owns 16 q-rows. KBLK=64.
// kt_s/vt_s/p_s XOR-swizzled (granule ^= row&7) for conflict-free ds_read_b128;
// staging via global_load_lds with inverse-swizzled SOURCE, linear LDS dest.
__global__ __launch_bounds__(256) void k_attn(const unsigned short* __restrict__ qb,
                                              const unsigned short* __restrict__ kb,
                                              const unsigned short* __restrict__ vT,
                                              unsigned short* __restrict__ ctxb) {
  // ---- load-balanced remap: CU c gets qtiles {q,31-q,(q+16)%32,31-(q+16)%32} ----
  const int n = blockIdx.y * 32 + blockIdx.x;   // 0..1023
  const int r = n >> 8, m_ = n & 255;
  const int mlow = m_ & 31, mhigh = m_ >> 5;
  const int bh = mhigh * 4 + r;
  int qt = (mlow + ((r >> 1) << 4)) & 31;
  if (r & 1) qt = 31 - qt;

  const int b = bh >> 4, h = bh & 15;
  const int kvh = h >> 2;
  const int tid = threadIdx.x, wid = tid >> 6, lane = tid & 63;
  const int lg = lane >> 4, ll = lane & 15;
  __shared__ unsigned short kt_s[64 * 128];   // [key][dh], swizzled
  __shared__ unsigned short vt_s[128 * 64];   // [dh][key], swizzled
  __shared__ unsigned short p_s[4 * 16 * 64]; // per-wave P, swizzled
  const char* ktc = (const char*)kt_s;
  const char* vtc = (const char*)vt_s;
  char* pwc = (char*)p_s + wid * 2048;
  const int swz = (ll & 7) << 4;              // read-side XOR (row&7 == ll&7 everywhere)

  const unsigned short* kbase = kb + (size_t)(b * NKVv + kvh) * Ss * DHh;
  const unsigned short* vbase = vT + (size_t)(b * NKVv + kvh) * DHh * Ss;
  const int qrow_f = qt * 64 + wid * 16 + ll;
  const unsigned short* qrow = qb + (size_t)(b * Ss + qrow_f) * NQq + h * DHh;
  bf16x8 qfr[4];
  #pragma unroll
  for (int ks = 0; ks < 4; ++ks)
    qfr[ks] = *(const bf16x8*)(const void*)(qrow + ks * 32 + lg * 8);
  f32x4 ctx[8] = {};
  float m_i[4], l_i[4];
  #pragma unroll
  for (int j = 0; j < 4; ++j) { m_i[j] = -1e30f; l_i[j] = 0.f; }
  const int qr0 = qt * 64 + wid * 16 + lg * 4;
  const int nkt = qt + 1;
  for (int kt = 0; kt < nkt; ++kt) {
    __syncthreads();
    // ---- stage K (64x128) and V^T (128x64): linear LDS dest, inv-swz source ----
    #pragma unroll
    for (int i = 0; i < 4; ++i) {
      const int s = i * 256 + tid;
      const int krow = s >> 4;
      const int kcs = (s & 15) ^ (krow & 7);
      const unsigned short* ksrc = kbase + (size_t)(kt * 64 + krow) * DHh + kcs * 8;
      __builtin_amdgcn_global_load_lds(
          (const __attribute__((address_space(1))) void*)ksrc,
          (__attribute__((address_space(3))) void*)(kt_s + (i * 256 + (wid << 6)) * 8), 16, 0, 0);
      const int vrow = s >> 3;
      const int vcs = (s & 7) ^ (vrow & 7);
      const unsigned short* vsrc = vbase + (size_t)vrow * Ss + kt * 64 + vcs * 8;
      __builtin_amdgcn_global_load_lds(
          (const __attribute__((address_space(1))) void*)vsrc,
          (__attribute__((address_space(3))) void*)(vt_s + (i * 256 + (wid << 6)) * 8), 16, 0, 0);
    }
    __syncthreads();
    // ---- QK^T ----
    f32x4 sc[4] = {};
    #pragma unroll
    for (int ks = 0; ks < 4; ++ks) {
      #pragma unroll
      for (int cb = 0; cb < 4; ++cb) {
        const bf16x8 kfr = *(const bf16x8*)(const void*)(
            ktc + ((cb * 16 + ll) << 8) + (((ks << 6) + (lg << 4)) ^ swz));
        sc[cb] = __builtin_amdgcn_mfma_f32_16x16x32_bf16(qfr[ks], kfr, sc[cb], 0, 0, 0);
      }
    }
    // ---- online softmax ----
    float pv[4][4], pmax[4];
    #pragma unroll
    for (int j = 0; j < 4; ++j) pmax[j] = -1e30f;
    const int keyb = kt * 64 + ll;
    #pragma unroll
    for (int cb = 0; cb < 4; ++cb)
      #pragma unroll
      for (int j = 0; j < 4; ++j) {
        float s = sc[cb][j];
        if (keyb + cb * 16 > qr0 + j) s = -1e30f;  // causal
        pv[cb][j] = s;
        pmax[j] = fmaxf(pmax[j], s);
      }
    #pragma unroll
    for (int j = 0; j < 4; ++j) {
      #pragma unroll
      for (int msk = 1; msk < 16; msk <<= 1)
        pmax[j] = fmaxf(pmax[j], __shfl_xor(pmax[j], msk));
    }
    float corr[4], psum[4];
    #pragma unroll
    for (int j = 0; j < 4; ++j) {
      const float mn = fmaxf(m_i[j], pmax[j]);
      corr[j] = __expf(m_i[j] - mn);
      m_i[j] = mn;
      psum[j] = 0.f;
    }
    #pragma unroll
    for (int cb = 0; cb < 4; ++cb)
      #pragma unroll
      for (int j = 0; j < 4; ++j) {
        const float p = __expf(pv[cb][j] - m_i[j]);
        pv[cb][j] = p;
        psum[j] += p;
      }
    #pragma unroll
    for (int j = 0; j < 4; ++j) {
      #pragma unroll
      for (int msk = 1; msk < 16; msk <<= 1)
        psum[j] += __shfl_xor(psum[j], msk);
      l_i[j] = l_i[j] * corr[j] + psum[j];
    }
    #pragma unroll
    for (int ob = 0; ob < 8; ++ob)
      #pragma unroll
      for (int j = 0; j < 4; ++j) ctx[ob][j] *= corr[j];
    // ---- P -> per-wave LDS (swizzled write; no barrier needed, same wave) ----
    #pragma unroll
    for (int cb = 0; cb < 4; ++cb)
      #pragma unroll
      for (int j = 0; j < 4; ++j) {
        const int prow = lg * 4 + j;
        *(unsigned short*)(pwc + (prow << 7) +
                           (((cb << 5) + (ll << 1)) ^ ((prow & 7) << 4))) = f2bf(pv[cb][j]);
      }
    // ---- PV ----
    #pragma unroll
    for (int k2 = 0; k2 < 2; ++k2) {
      const bf16x8 pa = *(const bf16x8*)(const void*)(
          pwc + (ll << 7) + (((k2 << 6) + (lg << 4)) ^ swz));
      #pragma unroll
      for (int ob = 0; ob < 8; ++ob) {
        const bf16x8 vfr = *(const bf16x8*)(const void*)(
            vtc + ((ob * 16 + ll) << 7) + (((k2 << 6) + (lg << 4)) ^ swz));
        ctx[ob] = __builtin_amdgcn_mfma_f32_16x16x32_bf16(pa, vfr, ctx[ob], 0, 0, 0);
      }
    }
  }
  #pragma unroll
  for (int j = 0; j < 4; ++j) {
    const float inv = 1.f / l_i[j];
    unsigned short* crow = ctxb + (size_t)(b * Ss + qr0 + j) * NQq + h * DHh;
    #pragma unroll
    for (int ob = 0; ob < 8; ++ob)
      crow[ob * 16 + ll] = f2bf(ctx[ob][j] * inv);
  }
}

extern "C" void kernel_launch(void* const* d_in, const int* in_sizes, int n_in,
                              void* d_out, int out_size, void* d_ws, size_t ws_size,
                              hipStream_t stream) {
  const float* x    = (const float*)d_in[0];
  const float* cosT = (const float*)d_in[1];
  const float* sinT = (const float*)d_in[2];
  // d_in[3] = mask (causal tril) -- implemented structurally
  const float* Wq   = (const float*)d_in[4];
  const float* Wk   = (const float*)d_in[5];
  const float* Wv   = (const float*)d_in[6];
  const float* Wo   = (const float*)d_in[7];
  float* out  = (float*)d_out;
  float* outK = out + (size_t)Mm_ * Dd;
  float* outV = outK + (size_t)Bb * NKVv * Ss * DHh;

  char* ws = (char*)d_ws;
  size_t off = 0;
  auto alloc = [&](size_t bytes) -> void* {
    void* p = ws + off;
    off += (bytes + 255) & ~(size_t)255;
    return p;
  };
  unsigned short* xb  = (unsigned short*)alloc((size_t)Mm_ * Dd * 2);
  unsigned short* wqT = (unsigned short*)alloc((size_t)NQq * Dd * 2);
  unsigned short* wkT = (unsigned short*)alloc((size_t)512 * Dd * 2);
  unsigned short* wvT = (unsigned short*)alloc((size_t)512 * Dd * 2);
  unsigned short* woT = (unsigned short*)alloc((size_t)Dd * NQq * 2);
  unsigned short* qfb = (unsigned short*)alloc((size_t)Mm_ * NQq * 2);
  float*          kf  = (float*)alloc((size_t)Mm_ * 512 * 4);
  float*          vf  = (float*)alloc((size_t)Mm_ * 512 * 4);
  unsigned short* kbb = (unsigned short*)alloc((size_t)Bb * NKVv * Ss * DHh * 2);
  unsigned short* vTb = (unsigned short*)alloc((size_t)Bb * NKVv * Ss * DHh * 2);
  unsigned short* ctxb= (unsigned short*)alloc((size_t)Mm_ * NQq * 2);
  if (off > ws_size) return;  // workspace too small: fail cleanly

  // 1. x -> bf16
  k_convert<<<(Mm_ * Dd / 4 + 255) / 256, 256, 0, stream>>>(x, xb, Mm_ * Dd / 4);
  // 2. weights -> bf16 transposed
  k_transpose<<<dim3(Dd / 32, Dd / 32), 256, 0, stream>>>(Wq, wqT, Dd, Dd);
  k_transpose<<<dim3(512 / 32, Dd / 32), 256, 0, stream>>>(Wk, wkT, Dd, 512);
  k_transpose<<<dim3(512 / 32, Dd / 32), 256, 0, stream>>>(Wv, wvT, Dd, 512);
  k_transpose<<<dim3(Dd / 32, Dd / 32), 256, 0, stream>>>(Wo, woT, Dd, Dd);
  // 3. projections
  k_gemm_bt<<<dim3(NQq / 128, Mm_ / 128), 256, 0, stream>>>(xb, wqT, (float*)nullptr, qfb, NQq, Dd);
  k_gemm_bt<<<dim3(512 / 128, Mm_ / 128), 256, 0, stream>>>(xb, wkT, kf, (unsigned short*)nullptr, 512, Dd);
  k_gemm_bt<<<dim3(512 / 128, Mm_ / 128), 256, 0, stream>>>(xb, wvT, vf, (unsigned short*)nullptr, 512, Dd);
  // 4. RoPE + cache outputs
  k_rope_k<<<(Mm_ * NKVv * 64 + 255) / 256, 256, 0, stream>>>(kf, cosT, sinT, outK, kbb);
  k_v_post<<<(Mm_ * NKVv * DHh + 255) / 256, 256, 0, stream>>>(vf, outV, vTb);
  k_rope_q<<<(Mm_ * NHh * 64 + 255) / 256, 256, 0, stream>>>(qfb, cosT, sinT);
  // 5. attention
  k_attn<<<dim3(Ss / 64, Bb * NHh), 256, 0, stream>>>(qfb, kbb, vTb, ctxb);
  // 6. output projection
  k_gemm_bt<<<dim3(Dd / 128, Mm_ / 128), 256, 0, stream>>>(ctxb, woT, out, (unsigned short*)nullptr, Dd, NQq);
}